// Round 1
// baseline (1106.630 us; speedup 1.0000x reference)
//
#include <hip/hip_runtime.h>
#include <hip/hip_bf16.h>

// GAT 3-layer + pool + dense head for MI355X (gfx950).
// Pipeline: CSR build -> al_e GEMM (folded, all 3 layers) -> per-layer
// [MFMA GEMM -> al_s/al_d -> CSR online-softmax aggregate] -> pool -> head.
// All feature tensors bf16 (fp32 accum); threshold is 2% relative.

typedef __attribute__((ext_vector_type(8))) short short8;
typedef __attribute__((ext_vector_type(4))) float floatx4;

#define DEV __device__ __forceinline__

DEV unsigned short f2b(float f) {
  union { float f; unsigned u; } v; v.f = f;
  unsigned r = v.u + 0x7FFFu + ((v.u >> 16) & 1u);  // RNE
  return (unsigned short)(r >> 16);
}
DEV float b2f(unsigned short u) {
  union { unsigned u; float f; } v; v.u = ((unsigned)u) << 16;
  return v.f;
}

// ---------------- CSR build ----------------
__global__ void k_deg(const int* __restrict__ dst, int* __restrict__ deg, int E) {
  int e = blockIdx.x * 256 + threadIdx.x;
  if (e < E) atomicAdd(&deg[dst[e]], 1);
}

__global__ __launch_bounds__(1024) void k_scan(const int* __restrict__ deg,
    int* __restrict__ rowptr, int* __restrict__ cursor, int N, int E) {
  __shared__ int sd[1024];
  __shared__ int s_carry;
  int tid = threadIdx.x;
  if (tid == 0) s_carry = 0;
  __syncthreads();
  for (int base = 0; base < N; base += 8192) {
    int i0 = base + tid * 8;
    int v[8]; int s = 0;
#pragma unroll
    for (int j = 0; j < 8; j++) { int i = i0 + j; v[j] = (i < N) ? deg[i] : 0; s += v[j]; }
    int carry = s_carry;
    sd[tid] = s;
    __syncthreads();
    for (int off = 1; off < 1024; off <<= 1) {
      int t = (tid >= off) ? sd[tid - off] : 0;
      __syncthreads();
      sd[tid] += t;
      __syncthreads();
    }
    int incl = sd[tid];
    int run = carry + incl - s;  // exclusive prefix
#pragma unroll
    for (int j = 0; j < 8; j++) {
      int i = i0 + j;
      if (i < N) { rowptr[i] = run; cursor[i] = run; }
      run += v[j];
    }
    __syncthreads();
    if (tid == 1023) s_carry = carry + incl;
    __syncthreads();
  }
  if (tid == 0) rowptr[N] = E;
}

__global__ void k_scatter(const int* __restrict__ src, const int* __restrict__ dst,
    int* __restrict__ cursor, int* __restrict__ csr_src, int* __restrict__ csr_eid, int E) {
  int e = blockIdx.x * 256 + threadIdx.x;
  if (e < E) {
    int d = dst[e];
    int pos = atomicAdd(&cursor[d], 1);
    csr_src[pos] = src[e];
    csr_eid[pos] = e;
  }
}

// ---------------- weight prep ----------------
// Wt[n][k] = bf16(W[k][n])
__global__ void k_wt(const float* __restrict__ W, unsigned short* __restrict__ Wt,
                     int K, int Nout) {
  int idx = blockIdx.x * 256 + threadIdx.x;
  if (idx < K * Nout) {
    int n = idx / K, k = idx - n * K;
    Wt[idx] = f2b(W[(size_t)k * Nout + n]);
  }
}

// Wept[j][c], j = L*4+h (12 rows used, 16 total), c in [0,64): sum_cc We_L[c, h*C+cc]*ae_L[h,cc]
__global__ void k_wep(const float* __restrict__ We1, const float* __restrict__ ae1,
                      const float* __restrict__ We2, const float* __restrict__ ae2,
                      const float* __restrict__ We3, const float* __restrict__ ae3,
                      unsigned short* __restrict__ Wept) {
  int t = blockIdx.x * 256 + threadIdx.x;  // 0..767
  int j = t >> 6, c = t & 63;
  int L = j >> 2, h = j & 3;
  const float* We = (L == 0) ? We1 : (L == 1) ? We2 : We3;
  const float* ae = (L == 0) ? ae1 : (L == 1) ? ae2 : ae3;
  int C = (L == 2) ? 128 : 64;
  int HC = 4 * C;
  float s = 0.f;
  for (int cc = 0; cc < C; cc++) s += We[(size_t)c * HC + h * C + cc] * ae[h * C + cc];
  Wept[j * 64 + c] = f2b(s);
  if (t < 256) {  // zero pad rows 12..15
    int jj = 12 + (t >> 6);
    Wept[jj * 64 + (t & 63)] = 0;
  }
}

// ---------------- GEMM: C[M,Nout] = A[M,K] @ Bt[Nout,K]^T ----------------
template<bool A_F32, bool OUT_F32>
__global__ __launch_bounds__(256) void k_gemm(const void* __restrict__ Ap,
    const unsigned short* __restrict__ Bt, void* __restrict__ Cp,
    int M, int Nout, int K) {
  __shared__ unsigned short As[64][40];  // +8 pad: bank spread, 16B-aligned rows
  __shared__ unsigned short Bs[64][40];
  const int tid = threadIdx.x;
  const int wave = tid >> 6, lane = tid & 63;
  const int quad = lane >> 4, l16 = lane & 15;
  const int m0 = blockIdx.x * 64, n0 = blockIdx.y * 64;
  const int arow = tid >> 2, acg = (tid & 3) * 8;
  floatx4 acc[4] = {{0,0,0,0},{0,0,0,0},{0,0,0,0},{0,0,0,0}};
  for (int k0 = 0; k0 < K; k0 += 32) {
    {
      int gm = m0 + arow;
      unsigned short tmp[8];
      if (A_F32) {
        const float* Af = (const float*)Ap;
        if (gm < M) {
          const float4* p = (const float4*)(Af + (size_t)gm * K + k0 + acg);
          float4 u0 = p[0], u1 = p[1];
          tmp[0]=f2b(u0.x); tmp[1]=f2b(u0.y); tmp[2]=f2b(u0.z); tmp[3]=f2b(u0.w);
          tmp[4]=f2b(u1.x); tmp[5]=f2b(u1.y); tmp[6]=f2b(u1.z); tmp[7]=f2b(u1.w);
        } else {
#pragma unroll
          for (int j = 0; j < 8; j++) tmp[j] = 0;
        }
      } else {
        const unsigned short* Ab = (const unsigned short*)Ap;
        uint4 u = {0,0,0,0};
        if (gm < M) u = *(const uint4*)(Ab + (size_t)gm * K + k0 + acg);
        *(uint4*)tmp = u;
      }
      *(uint4*)&As[arow][acg] = *(uint4*)tmp;
      int gn = n0 + arow;
      uint4 bv = {0,0,0,0};
      if (gn < Nout) bv = *(const uint4*)(Bt + (size_t)gn * K + k0 + acg);
      *(uint4*)&Bs[arow][acg] = bv;
    }
    __syncthreads();
    short8 a = *(const short8*)&As[wave * 16 + l16][quad * 8];
#pragma unroll
    for (int t = 0; t < 4; t++) {
      short8 b = *(const short8*)&Bs[t * 16 + l16][quad * 8];
      acc[t] = __builtin_amdgcn_mfma_f32_16x16x32_bf16(a, b, acc[t], 0, 0, 0);
    }
    __syncthreads();
  }
#pragma unroll
  for (int t = 0; t < 4; t++) {
#pragma unroll
    for (int r = 0; r < 4; r++) {
      int row = m0 + wave * 16 + quad * 4 + r;  // C/D: col=lane&15, row=quad*4+reg
      int col = n0 + t * 16 + l16;
      if (row < M && col < Nout) {
        float v = acc[t][r];
        if (OUT_F32) ((float*)Cp)[(size_t)row * Nout + col] = v;
        else ((unsigned short*)Cp)[(size_t)row * Nout + col] = f2b(v);
      }
    }
  }
}

// ---------------- self-loop al_e = mean of incoming al_e (linearity) ----------------
__global__ void k_loop_ale(const int* __restrict__ rowptr, const int* __restrict__ csr_eid,
                           float* __restrict__ ale, int N, int E) {
  int n = blockIdx.x * 256 + threadIdx.x;
  if (n >= N) return;
  int s = rowptr[n], e = rowptr[n + 1];
  float a[12];
#pragma unroll
  for (int j = 0; j < 12; j++) a[j] = 0.f;
  for (int p = s; p < e; p++) {
    int eid = csr_eid[p];
    const float4* r = (const float4*)(ale + (size_t)eid * 16);
    float4 v0 = r[0], v1 = r[1], v2 = r[2];
    a[0]+=v0.x; a[1]+=v0.y; a[2]+=v0.z; a[3]+=v0.w;
    a[4]+=v1.x; a[5]+=v1.y; a[6]+=v1.z; a[7]+=v1.w;
    a[8]+=v2.x; a[9]+=v2.y; a[10]+=v2.z; a[11]+=v2.w;
  }
  float inv = 1.0f / (float)((e - s) > 1 ? (e - s) : 1);
  float* o = ale + (size_t)(E + n) * 16;
#pragma unroll
  for (int j = 0; j < 12; j++) o[j] = a[j] * inv;
  o[12] = o[13] = o[14] = o[15] = 0.f;
}

// ---------------- al_s / al_d from hs ----------------
template<int VPL>
__global__ __launch_bounds__(256) void k_ald(const unsigned short* __restrict__ hs,
    const float* __restrict__ a_s, const float* __restrict__ a_d,
    float* __restrict__ als, float* __restrict__ ald, int N) {
  int node = blockIdx.x * 4 + (threadIdx.x >> 6);
  int lane = threadIdx.x & 63;
  if (node >= N) return;
  const int HC = 64 * VPL;
  const unsigned short* row = hs + (size_t)node * HC + lane * VPL;
  float vs = 0.f, vd = 0.f;
#pragma unroll
  for (int j = 0; j < VPL; j++) {
    float v = b2f(row[j]);
    vs += v * a_s[lane * VPL + j];
    vd += v * a_d[lane * VPL + j];
  }
#pragma unroll
  for (int off = 1; off < 16; off <<= 1) {
    vs += __shfl_xor(vs, off, 64);
    vd += __shfl_xor(vd, off, 64);
  }
  if ((lane & 15) == 0) {
    als[node * 4 + (lane >> 4)] = vs;
    ald[node * 4 + (lane >> 4)] = vd;
  }
}

// ---------------- CSR online-softmax aggregation, one wave per node ----------------
// MODE 0: concat heads, +bias, ReLU -> bf16. MODE 1: mean heads, +bias -> f32.
template<int VPL, int MODE>
__global__ __launch_bounds__(256) void k_agg(const unsigned short* __restrict__ hs,
    const int* __restrict__ rowptr, const int* __restrict__ csr_src,
    const int* __restrict__ csr_eid, const float* __restrict__ ale, int L,
    const float* __restrict__ als, const float* __restrict__ ald,
    const float* __restrict__ bias, unsigned short* __restrict__ outb,
    float* __restrict__ outf, int N, int E) {
  const int HC = 64 * VPL;
  __shared__ float s_w[4][64][4];
  __shared__ int s_s[4][64];
  int wave = threadIdx.x >> 6, lane = threadIdx.x & 63;
  int node = blockIdx.x * 4 + wave;
  if (node >= N) return;  // no __syncthreads in this kernel (per-wave LDS slices)
  int start = rowptr[node];
  int cnt = rowptr[node + 1] - start;
  int total = cnt + 1;  // + self-loop
  int head = lane >> 4;
  const float4 aldv = *(const float4*)(ald + node * 4);
  float m0=-1e30f, m1=-1e30f, m2=-1e30f, m3=-1e30f;
  float d0=0.f, d1=0.f, d2=0.f, d3=0.f;
  float acc[VPL];
#pragma unroll
  for (int j = 0; j < VPL; j++) acc[j] = 0.f;
  for (int base = 0; base < total; base += 64) {
    int ei = base + lane;
    bool active = ei < total;
    float a0=-1e30f, a1=-1e30f, a2=-1e30f, a3=-1e30f;
    int sidx = node;
    if (active) {
      const float* alep;
      if (ei < cnt) {
        sidx = csr_src[start + ei];
        int eid = csr_eid[start + ei];
        alep = ale + (size_t)eid * 16 + L * 4;
      } else {
        alep = ale + (size_t)(E + node) * 16 + L * 4;
      }
      float4 ev = *(const float4*)alep;
      float4 sv = *(const float4*)(als + sidx * 4);
      a0 = sv.x + aldv.x + ev.x;
      a1 = sv.y + aldv.y + ev.y;
      a2 = sv.z + aldv.z + ev.z;
      a3 = sv.w + aldv.w + ev.w;
      a0 = a0 > 0.f ? a0 : 0.2f * a0;
      a1 = a1 > 0.f ? a1 : 0.2f * a1;
      a2 = a2 > 0.f ? a2 : 0.2f * a2;
      a3 = a3 > 0.f ? a3 : 0.2f * a3;
    }
    float c0=a0, c1=a1, c2=a2, c3=a3;
#pragma unroll
    for (int off = 32; off > 0; off >>= 1) {
      c0 = fmaxf(c0, __shfl_xor(c0, off, 64));
      c1 = fmaxf(c1, __shfl_xor(c1, off, 64));
      c2 = fmaxf(c2, __shfl_xor(c2, off, 64));
      c3 = fmaxf(c3, __shfl_xor(c3, off, 64));
    }
    float n0v = fmaxf(m0, c0), n1v = fmaxf(m1, c1), n2v = fmaxf(m2, c2), n3v = fmaxf(m3, c3);
    float p0 = active ? __expf(a0 - n0v) : 0.f;
    float p1 = active ? __expf(a1 - n1v) : 0.f;
    float p2 = active ? __expf(a2 - n2v) : 0.f;
    float p3 = active ? __expf(a3 - n3v) : 0.f;
    float s0=p0, s1=p1, s2=p2, s3=p3;
#pragma unroll
    for (int off = 32; off > 0; off >>= 1) {
      s0 += __shfl_xor(s0, off, 64);
      s1 += __shfl_xor(s1, off, 64);
      s2 += __shfl_xor(s2, off, 64);
      s3 += __shfl_xor(s3, off, 64);
    }
    float r0 = __expf(m0 - n0v), r1 = __expf(m1 - n1v);
    float r2 = __expf(m2 - n2v), r3 = __expf(m3 - n3v);
    d0 = d0 * r0 + s0; d1 = d1 * r1 + s1; d2 = d2 * r2 + s2; d3 = d3 * r3 + s3;
    float rh = head == 0 ? r0 : head == 1 ? r1 : head == 2 ? r2 : r3;
#pragma unroll
    for (int j = 0; j < VPL; j++) acc[j] *= rh;
    m0 = n0v; m1 = n1v; m2 = n2v; m3 = n3v;
    s_w[wave][lane][0] = p0; s_w[wave][lane][1] = p1;
    s_w[wave][lane][2] = p2; s_w[wave][lane][3] = p3;
    s_s[wave][lane] = sidx;
    __threadfence_block();  // per-wave LDS visibility
    int chunk = total - base; if (chunk > 64) chunk = 64;
    for (int t = 0; t < chunk; t++) {
      float w = s_w[wave][t][head];
      int sp = s_s[wave][t];
      const unsigned short* rowp = hs + (size_t)sp * HC + lane * VPL;
      if constexpr (VPL == 4) {
        ushort4 u = *(const ushort4*)rowp;
        acc[0] += w * b2f(u.x); acc[1] += w * b2f(u.y);
        acc[2] += w * b2f(u.z); acc[3] += w * b2f(u.w);
      } else {
        ushort4 u0 = ((const ushort4*)rowp)[0];
        ushort4 u1 = ((const ushort4*)rowp)[1];
        acc[0] += w * b2f(u0.x); acc[1] += w * b2f(u0.y);
        acc[2] += w * b2f(u0.z); acc[3] += w * b2f(u0.w);
        acc[4] += w * b2f(u1.x); acc[5] += w * b2f(u1.y);
        acc[6] += w * b2f(u1.z); acc[7] += w * b2f(u1.w);
      }
    }
  }
  float dh = head == 0 ? d0 : head == 1 ? d1 : head == 2 ? d2 : d3;
  float inv = 1.0f / (dh + 1e-16f);
  if constexpr (MODE == 0) {
#pragma unroll
    for (int j = 0; j < VPL; j++) {
      float v = acc[j] * inv + bias[lane * VPL + j];
      v = fmaxf(v, 0.f);
      outb[(size_t)node * HC + lane * VPL + j] = f2b(v);
    }
  } else {
#pragma unroll
    for (int j = 0; j < VPL; j++) {
      float v = acc[j] * inv;
      v += __shfl_xor(v, 16, 64);
      v += __shfl_xor(v, 32, 64);
      acc[j] = v * 0.25f;
    }
    if (lane < 16) {
#pragma unroll
      for (int j = 0; j < VPL; j++)
        outf[(size_t)node * 128 + lane * VPL + j] = acc[j] + bias[lane * VPL + j];
    }
  }
}

// ---------------- pooling (batch is sorted) ----------------
__global__ __launch_bounds__(256) void k_pool(const float* __restrict__ out3,
    const int* __restrict__ bat, float* __restrict__ g, int* __restrict__ cntb, int N) {
  int wid = blockIdx.x * 4 + (threadIdx.x >> 6);
  int lane = threadIdx.x & 63;
  int per = (N + 255) / 256;
  int s = wid * per, e = s + per;
  if (e > N) e = N;
  if (s >= e) return;
  int cur = bat[s];
  float ax = 0.f, ay = 0.f; int run = 0;
  for (int n = s; n < e; n++) {
    int b = bat[n];
    if (b != cur) {
      atomicAdd(&g[cur * 128 + lane * 2], ax);
      atomicAdd(&g[cur * 128 + lane * 2 + 1], ay);
      if (lane == 0) atomicAdd(&cntb[cur], run);
      ax = 0.f; ay = 0.f; run = 0; cur = b;
    }
    float2 v = *(const float2*)(out3 + (size_t)n * 128 + lane * 2);
    ax += v.x; ay += v.y; run++;
  }
  atomicAdd(&g[cur * 128 + lane * 2], ax);
  atomicAdd(&g[cur * 128 + lane * 2 + 1], ay);
  if (lane == 0) atomicAdd(&cntb[cur], run);
}

// ---------------- final head ----------------
__global__ __launch_bounds__(320) void k_final(const float* __restrict__ g,
    const int* __restrict__ cntb, const float* __restrict__ Wa, const float* __restrict__ ba,
    const float* __restrict__ Wv, const float* __restrict__ bv, float* __restrict__ out) {
  __shared__ float gm[128];
  int b = blockIdx.x, t = threadIdx.x;
  if (t < 128) {
    float c = (float)cntb[b];
    gm[t] = g[b * 128 + t] / fmaxf(c, 1.f);
  }
  __syncthreads();
  if (t < 257) {
    float acc = 0.f;
    if (t < 256) {
      for (int k = 0; k < 128; k++) acc += gm[k] * Wa[k * 256 + t];
      acc += ba[t];
    } else {
      for (int k = 0; k < 128; k++) acc += gm[k] * Wv[k];
      acc += bv[0];
    }
    out[b * 257 + t] = acc;
  }
}

extern "C" void kernel_launch(void* const* d_in, const int* in_sizes, int n_in,
                              void* d_out, int out_size, void* d_ws, size_t ws_size,
                              hipStream_t stream) {
  const float* x   = (const float*)d_in[0];
  const int*   ei  = (const int*)  d_in[1];
  const float* ea  = (const float*)d_in[2];
  const int*   bat = (const int*)  d_in[3];
  const float* W1  = (const float*)d_in[4];
  const float* as1 = (const float*)d_in[5];
  const float* ad1 = (const float*)d_in[6];
  const float* We1 = (const float*)d_in[7];
  const float* ae1 = (const float*)d_in[8];
  const float* b1  = (const float*)d_in[9];
  const float* W2  = (const float*)d_in[10];
  const float* as2 = (const float*)d_in[11];
  const float* ad2 = (const float*)d_in[12];
  const float* We2 = (const float*)d_in[13];
  const float* ae2 = (const float*)d_in[14];
  const float* b2  = (const float*)d_in[15];
  const float* W3  = (const float*)d_in[16];
  const float* as3 = (const float*)d_in[17];
  const float* ad3 = (const float*)d_in[18];
  const float* We3 = (const float*)d_in[19];
  const float* ae3 = (const float*)d_in[20];
  const float* b3  = (const float*)d_in[21];
  const float* Wa  = (const float*)d_in[22];
  const float* ba  = (const float*)d_in[23];
  const float* Wv  = (const float*)d_in[24];
  const float* bv  = (const float*)d_in[25];
  (void)n_in; (void)out_size; (void)ws_size;

  const int N = in_sizes[0] / 192;  // 50000
  const int E = in_sizes[1] / 2;    // 800000
  const int* srcv = ei;
  const int* dstv = ei + E;

  size_t off = 0;
  auto alloc = [&](size_t bytes) -> char* {
    char* p = (char*)d_ws + off;
    off += (bytes + 255) & ~(size_t)255;
    return p;
  };
  int* deg     = (int*)alloc((size_t)N * 4);
  int* rowptr  = (int*)alloc((size_t)(N + 1) * 4);
  int* cursor  = (int*)alloc((size_t)N * 4);
  int* csr_src = (int*)alloc((size_t)E * 4);
  int* csr_eid = (int*)alloc((size_t)E * 4);
  float* ale   = (float*)alloc((size_t)(E + N) * 16 * 4);   // [E+N][16] (12 used: 3 layers x 4 heads)
  unsigned short* Wept = (unsigned short*)alloc(16 * 64 * 2);
  unsigned short* W1t  = (unsigned short*)alloc(256 * 192 * 2);
  unsigned short* W2t  = (unsigned short*)alloc(256 * 256 * 2);
  unsigned short* W3t  = (unsigned short*)alloc(512 * 256 * 2);
  unsigned short* hs   = (unsigned short*)alloc((size_t)N * 512 * 2);
  unsigned short* h1   = (unsigned short*)alloc((size_t)N * 256 * 2);
  unsigned short* h2   = (unsigned short*)alloc((size_t)N * 256 * 2);
  float* out3  = (float*)alloc((size_t)N * 128 * 4);
  float* als   = (float*)alloc((size_t)N * 4 * 4);
  float* ald   = (float*)alloc((size_t)N * 4 * 4);
  float* g     = (float*)alloc(64 * 128 * 4 + 64 * 4);
  int* cntb    = (int*)(g + 64 * 128);

  hipMemsetAsync(deg, 0, (size_t)N * 4, stream);
  hipMemsetAsync(g, 0, 64 * 128 * 4 + 64 * 4, stream);

  k_deg<<<(E + 255) / 256, 256, 0, stream>>>(dstv, deg, E);
  k_scan<<<1, 1024, 0, stream>>>(deg, rowptr, cursor, N, E);
  k_scatter<<<(E + 255) / 256, 256, 0, stream>>>(srcv, dstv, cursor, csr_src, csr_eid, E);
  k_wt<<<(192 * 256 + 255) / 256, 256, 0, stream>>>(W1, W1t, 192, 256);
  k_wt<<<(256 * 256 + 255) / 256, 256, 0, stream>>>(W2, W2t, 256, 256);
  k_wt<<<(256 * 512 + 255) / 256, 256, 0, stream>>>(W3, W3t, 256, 512);
  k_wep<<<3, 256, 0, stream>>>(We1, ae1, We2, ae2, We3, ae3, Wept);
  // al_e for all 3 layers in one GEMM over edge_attr
  k_gemm<true, true><<<dim3((E + 63) / 64, 1), 256, 0, stream>>>(ea, Wept, ale, E, 16, 64);
  k_loop_ale<<<(N + 255) / 256, 256, 0, stream>>>(rowptr, csr_eid, ale, N, E);
  // layer 1
  k_gemm<true, false><<<dim3((N + 63) / 64, 4), 256, 0, stream>>>(x, W1t, hs, N, 256, 192);
  k_ald<4><<<(N + 3) / 4, 256, 0, stream>>>(hs, as1, ad1, als, ald, N);
  k_agg<4, 0><<<(N + 3) / 4, 256, 0, stream>>>(hs, rowptr, csr_src, csr_eid, ale, 0, als, ald, b1, h1, nullptr, N, E);
  // layer 2
  k_gemm<false, false><<<dim3((N + 63) / 64, 4), 256, 0, stream>>>(h1, W2t, hs, N, 256, 256);
  k_ald<4><<<(N + 3) / 4, 256, 0, stream>>>(hs, as2, ad2, als, ald, N);
  k_agg<4, 0><<<(N + 3) / 4, 256, 0, stream>>>(hs, rowptr, csr_src, csr_eid, ale, 1, als, ald, b2, h2, nullptr, N, E);
  // layer 3
  k_gemm<false, false><<<dim3((N + 63) / 64, 8), 256, 0, stream>>>(h2, W3t, hs, N, 512, 256);
  k_ald<8><<<(N + 3) / 4, 256, 0, stream>>>(hs, as3, ad3, als, ald, N);
  k_agg<8, 1><<<(N + 3) / 4, 256, 0, stream>>>(hs, rowptr, csr_src, csr_eid, ale, 2, als, ald, b3, nullptr, out3, N, E);
  // pool + head
  k_pool<<<64, 256, 0, stream>>>(out3, bat, g, cntb, N);
  k_final<<<64, 320, 0, stream>>>(g, cntb, Wa, ba, Wv, bv, (float*)d_out);
}

// Round 2
// 1064.049 us; speedup vs baseline: 1.0400x; 1.0400x over previous
//
#include <hip/hip_runtime.h>
#include <hip/hip_bf16.h>

// GAT 3-layer + pool + dense head for MI355X (gfx950).
// R2: k_agg restructured to 16-lanes-per-node (4 nodes/wave) for 4x gather MLP;
// k_ald folded into GEMM epilogue; ale stored layer-major; 3-kernel scan.

typedef __attribute__((ext_vector_type(8))) short short8;
typedef __attribute__((ext_vector_type(4))) float floatx4;

#define DEV __device__ __forceinline__

DEV unsigned short f2b(float f) {
  union { float f; unsigned u; } v; v.f = f;
  unsigned r = v.u + 0x7FFFu + ((v.u >> 16) & 1u);  // RNE
  return (unsigned short)(r >> 16);
}
DEV float b2f(unsigned short u) {
  union { unsigned u; float f; } v; v.u = ((unsigned)u) << 16;
  return v.f;
}

// ---------------- CSR build ----------------
__global__ void k_deg(const int* __restrict__ dst, int* __restrict__ deg, int E) {
  int e = blockIdx.x * 256 + threadIdx.x;
  if (e < E) atomicAdd(&deg[dst[e]], 1);
}

// block-local exclusive scan over 1024 elems (256 thr x 4)
__global__ __launch_bounds__(256) void k_scan1(const int* __restrict__ deg,
    int* __restrict__ rowptr, int* __restrict__ bsum, int N) {
  __shared__ int sd[256];
  int b = blockIdx.x, tid = threadIdx.x;
  int i0 = b * 1024 + tid * 4;
  int v[4]; int s = 0;
#pragma unroll
  for (int j = 0; j < 4; j++) { int i = i0 + j; v[j] = (i < N) ? deg[i] : 0; s += v[j]; }
  sd[tid] = s;
  __syncthreads();
  for (int off = 1; off < 256; off <<= 1) {
    int t = (tid >= off) ? sd[tid - off] : 0;
    __syncthreads();
    sd[tid] += t;
    __syncthreads();
  }
  int run = sd[tid] - s;  // exclusive
#pragma unroll
  for (int j = 0; j < 4; j++) { int i = i0 + j; if (i < N) rowptr[i] = run; run += v[j]; }
  if (tid == 255) bsum[b] = sd[255];
}

__global__ __launch_bounds__(256) void k_scan2(int* __restrict__ bsum, int nb) {
  __shared__ int sd[256];
  int tid = threadIdx.x;
  int v = (tid < nb) ? bsum[tid] : 0;
  sd[tid] = v;
  __syncthreads();
  for (int off = 1; off < 256; off <<= 1) {
    int t = (tid >= off) ? sd[tid - off] : 0;
    __syncthreads();
    sd[tid] += t;
    __syncthreads();
  }
  if (tid < nb) bsum[tid] = sd[tid] - v;  // exclusive
}

__global__ __launch_bounds__(256) void k_scan3(int* __restrict__ rowptr,
    int* __restrict__ cursor, const int* __restrict__ bsum, int N, int E) {
  int b = blockIdx.x, tid = threadIdx.x;
  int add = bsum[b];
  int i0 = b * 1024 + tid * 4;
#pragma unroll
  for (int j = 0; j < 4; j++) {
    int i = i0 + j;
    if (i < N) { int r = rowptr[i] + add; rowptr[i] = r; cursor[i] = r; }
  }
  if (b == 0 && tid == 0) rowptr[N] = E;
}

__global__ void k_scatter(const int* __restrict__ src, const int* __restrict__ dst,
    int* __restrict__ cursor, int2* __restrict__ csr, int E) {
  int e = blockIdx.x * 256 + threadIdx.x;
  if (e < E) {
    int d = dst[e];
    int pos = atomicAdd(&cursor[d], 1);
    csr[pos] = make_int2(src[e], e);
  }
}

// ---------------- weight prep ----------------
__global__ void k_wt(const float* __restrict__ W, unsigned short* __restrict__ Wt,
                     int K, int Nout) {
  int idx = blockIdx.x * 256 + threadIdx.x;
  if (idx < K * Nout) {
    int n = idx / K, k = idx - n * K;
    Wt[idx] = f2b(W[(size_t)k * Nout + n]);
  }
}

// Wept[j][c], j = L*4+h (12 rows used, 16 total)
__global__ void k_wep(const float* __restrict__ We1, const float* __restrict__ ae1,
                      const float* __restrict__ We2, const float* __restrict__ ae2,
                      const float* __restrict__ We3, const float* __restrict__ ae3,
                      unsigned short* __restrict__ Wept) {
  int t = blockIdx.x * 256 + threadIdx.x;  // 0..767
  int j = t >> 6, c = t & 63;
  int L = j >> 2, h = j & 3;
  const float* We = (L == 0) ? We1 : (L == 1) ? We2 : We3;
  const float* ae = (L == 0) ? ae1 : (L == 1) ? ae2 : ae3;
  int C = (L == 2) ? 128 : 64;
  int HC = 4 * C;
  float s = 0.f;
  for (int cc = 0; cc < C; cc++) s += We[(size_t)c * HC + h * C + cc] * ae[h * C + cc];
  Wept[j * 64 + c] = f2b(s);
  if (t < 256) {
    int jj = 12 + (t >> 6);
    Wept[jj * 64 + (t & 63)] = 0;
  }
}

// ---------------- GEMM: C[M,Nout] = A[M,K] @ Bt[Nout,K]^T ----------------
// OUT_MODE: 0 = bf16 C; 2 = ale layer-major f32 ([L][EN][4], col=L*4+h, col<12)
// DO_ALD: epilogue also accumulates als/ald (head = n0*4/Nout, uniform per block)
template<bool A_F32, int OUT_MODE, bool DO_ALD>
__global__ __launch_bounds__(256) void k_gemm(const void* __restrict__ Ap,
    const unsigned short* __restrict__ Bt, void* __restrict__ Cp,
    int M, int Nout, int K, int EN,
    const float* __restrict__ a_s, const float* __restrict__ a_d,
    float* __restrict__ als, float* __restrict__ ald) {
  __shared__ unsigned short As[64][40];
  __shared__ unsigned short Bs[64][40];
  const int tid = threadIdx.x;
  const int wave = tid >> 6, lane = tid & 63;
  const int quad = lane >> 4, l16 = lane & 15;
  const int m0 = blockIdx.x * 64, n0 = blockIdx.y * 64;
  const int arow = tid >> 2, acg = (tid & 3) * 8;
  floatx4 acc[4] = {{0,0,0,0},{0,0,0,0},{0,0,0,0},{0,0,0,0}};
  for (int k0 = 0; k0 < K; k0 += 32) {
    {
      int gm = m0 + arow;
      unsigned short tmp[8];
      if (A_F32) {
        const float* Af = (const float*)Ap;
        if (gm < M) {
          const float4* p = (const float4*)(Af + (size_t)gm * K + k0 + acg);
          float4 u0 = p[0], u1 = p[1];
          tmp[0]=f2b(u0.x); tmp[1]=f2b(u0.y); tmp[2]=f2b(u0.z); tmp[3]=f2b(u0.w);
          tmp[4]=f2b(u1.x); tmp[5]=f2b(u1.y); tmp[6]=f2b(u1.z); tmp[7]=f2b(u1.w);
        } else {
#pragma unroll
          for (int j = 0; j < 8; j++) tmp[j] = 0;
        }
      } else {
        const unsigned short* Ab = (const unsigned short*)Ap;
        uint4 u = {0,0,0,0};
        if (gm < M) u = *(const uint4*)(Ab + (size_t)gm * K + k0 + acg);
        *(uint4*)tmp = u;
      }
      *(uint4*)&As[arow][acg] = *(uint4*)tmp;
      int gn = n0 + arow;
      uint4 bv = {0,0,0,0};
      if (gn < Nout) bv = *(const uint4*)(Bt + (size_t)gn * K + k0 + acg);
      *(uint4*)&Bs[arow][acg] = bv;
    }
    __syncthreads();
    short8 a = *(const short8*)&As[wave * 16 + l16][quad * 8];
#pragma unroll
    for (int t = 0; t < 4; t++) {
      short8 b = *(const short8*)&Bs[t * 16 + l16][quad * 8];
      acc[t] = __builtin_amdgcn_mfma_f32_16x16x32_bf16(a, b, acc[t], 0, 0, 0);
    }
    __syncthreads();
  }
#pragma unroll
  for (int t = 0; t < 4; t++) {
#pragma unroll
    for (int r = 0; r < 4; r++) {
      int row = m0 + wave * 16 + quad * 4 + r;  // C/D: col=lane&15, row=quad*4+reg
      int col = n0 + t * 16 + l16;
      float v = acc[t][r];
      if (OUT_MODE == 0) {
        if (row < M && col < Nout)
          ((unsigned short*)Cp)[(size_t)row * Nout + col] = f2b(v);
      } else {  // ale layer-major
        if (row < M && col < 12)
          ((float*)Cp)[((size_t)(col >> 2) * EN + row) * 4 + (col & 3)] = v;
      }
    }
  }
  if constexpr (DO_ALD) {
    int h = (n0 * 4) / Nout;
#pragma unroll
    for (int r = 0; r < 4; r++) {
      float ps = 0.f, pd = 0.f;
#pragma unroll
      for (int t = 0; t < 4; t++) {
        int col = n0 + t * 16 + l16;
        float v = acc[t][r];
        ps += v * a_s[col];
        pd += v * a_d[col];
      }
#pragma unroll
      for (int off = 1; off < 16; off <<= 1) {
        ps += __shfl_xor(ps, off, 64);
        pd += __shfl_xor(pd, off, 64);
      }
      int row = m0 + wave * 16 + quad * 4 + r;
      if (l16 == 0 && row < M) {
        atomicAdd(&als[row * 4 + h], ps);
        atomicAdd(&ald[row * 4 + h], pd);
      }
    }
  }
}

// ---------------- self-loop al_e = mean of incoming al_e ----------------
__global__ void k_loop_ale(const int* __restrict__ rowptr, const int2* __restrict__ csr,
                           float* __restrict__ ale, int N, int E) {
  int n = blockIdx.x * 256 + threadIdx.x;
  if (n >= N) return;
  const size_t EN = (size_t)E + N;
  int s = rowptr[n], e = rowptr[n + 1];
  float a[12];
#pragma unroll
  for (int j = 0; j < 12; j++) a[j] = 0.f;
  for (int p = s; p < e; p++) {
    int eid = csr[p].y;
#pragma unroll
    for (int L = 0; L < 3; L++) {
      float4 v = *(const float4*)(ale + (L * EN + eid) * 4);
      a[L * 4 + 0] += v.x; a[L * 4 + 1] += v.y;
      a[L * 4 + 2] += v.z; a[L * 4 + 3] += v.w;
    }
  }
  float inv = 1.0f / (float)((e - s) > 1 ? (e - s) : 1);
#pragma unroll
  for (int L = 0; L < 3; L++)
    *(float4*)(ale + (L * EN + E + n) * 4) =
        make_float4(a[L*4+0]*inv, a[L*4+1]*inv, a[L*4+2]*inv, a[L*4+3]*inv);
}

// ---------------- CSR online-softmax aggregation ----------------
// 16 lanes per node, 4 nodes per wave, 16 nodes per block.
// VPL: features per lane (16 -> HC=256, 32 -> HC=512).
// MODE 0: concat heads, +bias, ReLU -> bf16. MODE 1: mean heads, +bias -> f32.
template<int VPL, int MODE>
__global__ __launch_bounds__(256) void k_agg(const unsigned short* __restrict__ hs,
    const int* __restrict__ rowptr, const int2* __restrict__ csr,
    const float* __restrict__ ale,  // layer base, [EN][4]
    const float* __restrict__ als, const float* __restrict__ ald,
    const float* __restrict__ bias, unsigned short* __restrict__ outb,
    float* __restrict__ outf, int N, int E) {
  const int HC = 16 * VPL;
  __shared__ float s_w[4][4][16][4];
  __shared__ int   s_s[4][4][16];
  const int wave = threadIdx.x >> 6;
  const int lane = threadIdx.x & 63;
  const int grp  = lane >> 4;
  const int sl   = lane & 15;
  const int hd   = sl >> 2;  // lane's feature slice lives in this head
  const int node = blockIdx.x * 16 + wave * 4 + grp;
  if (node >= N) return;  // no __syncthreads in this kernel
  int start = rowptr[node];
  int cnt   = rowptr[node + 1] - start;
  int total = cnt + 1;  // + self-loop
  const float4 aldv = *(const float4*)(ald + node * 4);
  float m0=-1e30f, m1=-1e30f, m2=-1e30f, m3=-1e30f;
  float d0=0.f, d1=0.f, d2=0.f, d3=0.f;
  float acc[VPL];
#pragma unroll
  for (int j = 0; j < VPL; j++) acc[j] = 0.f;
  for (int base = 0; base < total; base += 16) {
    int ei = base + sl;
    bool active = ei < total;
    float a0=-1e30f, a1=-1e30f, a2=-1e30f, a3=-1e30f;
    int sidx = node;
    if (active) {
      const float* alep;
      if (ei < cnt) {
        int2 se = csr[start + ei];
        sidx = se.x;
        alep = ale + (size_t)se.y * 4;
      } else {
        alep = ale + ((size_t)E + node) * 4;
      }
      float4 ev = *(const float4*)alep;
      float4 sv = *(const float4*)(als + sidx * 4);
      a0 = sv.x + aldv.x + ev.x;
      a1 = sv.y + aldv.y + ev.y;
      a2 = sv.z + aldv.z + ev.z;
      a3 = sv.w + aldv.w + ev.w;
      a0 = a0 > 0.f ? a0 : 0.2f * a0;
      a1 = a1 > 0.f ? a1 : 0.2f * a1;
      a2 = a2 > 0.f ? a2 : 0.2f * a2;
      a3 = a3 > 0.f ? a3 : 0.2f * a3;
    }
    float c0=a0, c1=a1, c2=a2, c3=a3;
#pragma unroll
    for (int off = 8; off > 0; off >>= 1) {
      c0 = fmaxf(c0, __shfl_xor(c0, off, 64));
      c1 = fmaxf(c1, __shfl_xor(c1, off, 64));
      c2 = fmaxf(c2, __shfl_xor(c2, off, 64));
      c3 = fmaxf(c3, __shfl_xor(c3, off, 64));
    }
    float n0v = fmaxf(m0, c0), n1v = fmaxf(m1, c1), n2v = fmaxf(m2, c2), n3v = fmaxf(m3, c3);
    float p0 = active ? __expf(a0 - n0v) : 0.f;
    float p1 = active ? __expf(a1 - n1v) : 0.f;
    float p2 = active ? __expf(a2 - n2v) : 0.f;
    float p3 = active ? __expf(a3 - n3v) : 0.f;
    float s0=p0, s1=p1, s2=p2, s3=p3;
#pragma unroll
    for (int off = 8; off > 0; off >>= 1) {
      s0 += __shfl_xor(s0, off, 64);
      s1 += __shfl_xor(s1, off, 64);
      s2 += __shfl_xor(s2, off, 64);
      s3 += __shfl_xor(s3, off, 64);
    }
    float r0 = __expf(m0 - n0v), r1 = __expf(m1 - n1v);
    float r2 = __expf(m2 - n2v), r3 = __expf(m3 - n3v);
    d0 = d0 * r0 + s0; d1 = d1 * r1 + s1; d2 = d2 * r2 + s2; d3 = d3 * r3 + s3;
    float rh = hd == 0 ? r0 : hd == 1 ? r1 : hd == 2 ? r2 : r3;
#pragma unroll
    for (int j = 0; j < VPL; j++) acc[j] *= rh;
    m0 = n0v; m1 = n1v; m2 = n2v; m3 = n3v;
    *(float4*)&s_w[wave][grp][sl][0] = make_float4(p0, p1, p2, p3);
    s_s[wave][grp][sl] = sidx;
    __threadfence_block();  // per-wave LDS visibility
    int chunk = total - base; if (chunk > 16) chunk = 16;
    int t = 0;
    for (; t + 2 <= chunk; t += 2) {
      float w0 = s_w[wave][grp][t][hd];     int sp0 = s_s[wave][grp][t];
      float w1 = s_w[wave][grp][t + 1][hd]; int sp1 = s_s[wave][grp][t + 1];
      const unsigned short* r0p = hs + (size_t)sp0 * HC + sl * VPL;
      const unsigned short* r1p = hs + (size_t)sp1 * HC + sl * VPL;
      unsigned short v0[VPL], v1[VPL];
#pragma unroll
      for (int q = 0; q < VPL / 8; q++) ((uint4*)v0)[q] = ((const uint4*)r0p)[q];
#pragma unroll
      for (int q = 0; q < VPL / 8; q++) ((uint4*)v1)[q] = ((const uint4*)r1p)[q];
#pragma unroll
      for (int j = 0; j < VPL; j++) acc[j] += w0 * b2f(v0[j]);
#pragma unroll
      for (int j = 0; j < VPL; j++) acc[j] += w1 * b2f(v1[j]);
    }
    if (t < chunk) {
      float w0 = s_w[wave][grp][t][hd]; int sp0 = s_s[wave][grp][t];
      const unsigned short* r0p = hs + (size_t)sp0 * HC + sl * VPL;
      unsigned short v0[VPL];
#pragma unroll
      for (int q = 0; q < VPL / 8; q++) ((uint4*)v0)[q] = ((const uint4*)r0p)[q];
#pragma unroll
      for (int j = 0; j < VPL; j++) acc[j] += w0 * b2f(v0[j]);
    }
  }
  float dh = hd == 0 ? d0 : hd == 1 ? d1 : hd == 2 ? d2 : d3;
  float inv = 1.0f / (dh + 1e-16f);
  if constexpr (MODE == 0) {
    unsigned short tmp[VPL];
#pragma unroll
    for (int j = 0; j < VPL; j++) {
      float v = acc[j] * inv + bias[sl * VPL + j];
      tmp[j] = f2b(fmaxf(v, 0.f));
    }
    unsigned short* op = outb + (size_t)node * HC + sl * VPL;
#pragma unroll
    for (int q = 0; q < VPL / 8; q++) ((uint4*)op)[q] = ((uint4*)tmp)[q];
  } else {
    // mean over heads: lane sl covers hs cols [sl*VPL, sl*VPL+VPL); head=sl>>2,
    // out col c = (sl&3)*VPL + j. Sum lanes sl^4, sl^8.
#pragma unroll
    for (int j = 0; j < VPL; j++) {
      float v = acc[j] * inv;
      v += __shfl_xor(v, 4, 64);
      v += __shfl_xor(v, 8, 64);
      acc[j] = v * 0.25f;
    }
    if (sl < 4) {
      float* op = outf + (size_t)node * (4 * VPL) + sl * VPL;
#pragma unroll
      for (int j = 0; j < VPL; j++) op[j] = acc[j] + bias[sl * VPL + j];
    }
  }
}

// ---------------- pooling (batch is sorted) ----------------
__global__ __launch_bounds__(256) void k_pool(const float* __restrict__ out3,
    const int* __restrict__ bat, float* __restrict__ g, int* __restrict__ cntb, int N) {
  int wid = blockIdx.x * 4 + (threadIdx.x >> 6);
  int lane = threadIdx.x & 63;
  int per = (N + 255) / 256;
  int s = wid * per, e = s + per;
  if (e > N) e = N;
  if (s >= e) return;
  int cur = bat[s];
  float ax = 0.f, ay = 0.f; int run = 0;
  for (int n = s; n < e; n++) {
    int b = bat[n];
    if (b != cur) {
      atomicAdd(&g[cur * 128 + lane * 2], ax);
      atomicAdd(&g[cur * 128 + lane * 2 + 1], ay);
      if (lane == 0) atomicAdd(&cntb[cur], run);
      ax = 0.f; ay = 0.f; run = 0; cur = b;
    }
    float2 v = *(const float2*)(out3 + (size_t)n * 128 + lane * 2);
    ax += v.x; ay += v.y; run++;
  }
  atomicAdd(&g[cur * 128 + lane * 2], ax);
  atomicAdd(&g[cur * 128 + lane * 2 + 1], ay);
  if (lane == 0) atomicAdd(&cntb[cur], run);
}

// ---------------- final head ----------------
__global__ __launch_bounds__(320) void k_final(const float* __restrict__ g,
    const int* __restrict__ cntb, const float* __restrict__ Wa, const float* __restrict__ ba,
    const float* __restrict__ Wv, const float* __restrict__ bv, float* __restrict__ out) {
  __shared__ float gm[128];
  int b = blockIdx.x, t = threadIdx.x;
  if (t < 128) {
    float c = (float)cntb[b];
    gm[t] = g[b * 128 + t] / fmaxf(c, 1.f);
  }
  __syncthreads();
  if (t < 257) {
    float acc = 0.f;
    if (t < 256) {
      for (int k = 0; k < 128; k++) acc += gm[k] * Wa[k * 256 + t];
      acc += ba[t];
    } else {
      for (int k = 0; k < 128; k++) acc += gm[k] * Wv[k];
      acc += bv[0];
    }
    out[b * 257 + t] = acc;
  }
}

extern "C" void kernel_launch(void* const* d_in, const int* in_sizes, int n_in,
                              void* d_out, int out_size, void* d_ws, size_t ws_size,
                              hipStream_t stream) {
  const float* x   = (const float*)d_in[0];
  const int*   ei  = (const int*)  d_in[1];
  const float* ea  = (const float*)d_in[2];
  const int*   bat = (const int*)  d_in[3];
  const float* W1  = (const float*)d_in[4];
  const float* as1 = (const float*)d_in[5];
  const float* ad1 = (const float*)d_in[6];
  const float* We1 = (const float*)d_in[7];
  const float* ae1 = (const float*)d_in[8];
  const float* b1  = (const float*)d_in[9];
  const float* W2  = (const float*)d_in[10];
  const float* as2 = (const float*)d_in[11];
  const float* ad2 = (const float*)d_in[12];
  const float* We2 = (const float*)d_in[13];
  const float* ae2 = (const float*)d_in[14];
  const float* b2  = (const float*)d_in[15];
  const float* W3  = (const float*)d_in[16];
  const float* as3 = (const float*)d_in[17];
  const float* ad3 = (const float*)d_in[18];
  const float* We3 = (const float*)d_in[19];
  const float* ae3 = (const float*)d_in[20];
  const float* b3  = (const float*)d_in[21];
  const float* Wa  = (const float*)d_in[22];
  const float* ba  = (const float*)d_in[23];
  const float* Wv  = (const float*)d_in[24];
  const float* bv  = (const float*)d_in[25];
  (void)n_in; (void)out_size; (void)ws_size;

  const int N = in_sizes[0] / 192;  // 50000
  const int E = in_sizes[1] / 2;    // 800000
  const size_t EN = (size_t)E + N;
  const int* srcv = ei;
  const int* dstv = ei + E;
  const int nb = (N + 1023) / 1024;

  size_t off = 0;
  auto alloc = [&](size_t bytes) -> char* {
    char* p = (char*)d_ws + off;
    off += (bytes + 255) & ~(size_t)255;
    return p;
  };
  int* deg     = (int*)alloc((size_t)N * 4);
  int* rowptr  = (int*)alloc((size_t)(N + 1) * 4);
  int* cursor  = (int*)alloc((size_t)N * 4);
  int* bsum    = (int*)alloc(256 * 4);
  int2* csr    = (int2*)alloc((size_t)E * 8);
  float* ale   = (float*)alloc(3 * EN * 4 * 4);  // [L][EN][4]
  unsigned short* Wept = (unsigned short*)alloc(16 * 64 * 2);
  unsigned short* W1t  = (unsigned short*)alloc(256 * 192 * 2);
  unsigned short* W2t  = (unsigned short*)alloc(256 * 256 * 2);
  unsigned short* W3t  = (unsigned short*)alloc(512 * 256 * 2);
  unsigned short* hs   = (unsigned short*)alloc((size_t)N * 512 * 2);
  unsigned short* h1   = (unsigned short*)alloc((size_t)N * 256 * 2);
  unsigned short* h2   = (unsigned short*)alloc((size_t)N * 256 * 2);
  float* out3  = (float*)alloc((size_t)N * 128 * 4);
  float* als_all = (float*)alloc((size_t)N * 4 * 4 * 6);  // als1,ald1,als2,ald2,als3,ald3
  float* g     = (float*)alloc(64 * 128 * 4 + 64 * 4);
  int* cntb    = (int*)(g + 64 * 128);
  float* als1 = als_all + (size_t)N * 4 * 0;
  float* ald1 = als_all + (size_t)N * 4 * 1;
  float* als2 = als_all + (size_t)N * 4 * 2;
  float* ald2 = als_all + (size_t)N * 4 * 3;
  float* als3 = als_all + (size_t)N * 4 * 4;
  float* ald3 = als_all + (size_t)N * 4 * 5;

  hipMemsetAsync(deg, 0, (size_t)N * 4, stream);
  hipMemsetAsync(als_all, 0, (size_t)N * 4 * 4 * 6, stream);
  hipMemsetAsync(g, 0, 64 * 128 * 4 + 64 * 4, stream);

  k_deg<<<(E + 255) / 256, 256, 0, stream>>>(dstv, deg, E);
  k_scan1<<<nb, 256, 0, stream>>>(deg, rowptr, bsum, N);
  k_scan2<<<1, 256, 0, stream>>>(bsum, nb);
  k_scan3<<<nb, 256, 0, stream>>>(rowptr, cursor, bsum, N, E);
  k_scatter<<<(E + 255) / 256, 256, 0, stream>>>(srcv, dstv, cursor, csr, E);
  k_wt<<<(192 * 256 + 255) / 256, 256, 0, stream>>>(W1, W1t, 192, 256);
  k_wt<<<(256 * 256 + 255) / 256, 256, 0, stream>>>(W2, W2t, 256, 256);
  k_wt<<<(256 * 512 + 255) / 256, 256, 0, stream>>>(W3, W3t, 256, 512);
  k_wep<<<3, 256, 0, stream>>>(We1, ae1, We2, ae2, We3, ae3, Wept);
  // al_e for all 3 layers in one GEMM over edge_attr (layer-major output)
  k_gemm<true, 2, false><<<dim3((E + 63) / 64, 1), 256, 0, stream>>>(
      ea, Wept, ale, E, 16, 64, (int)EN, nullptr, nullptr, nullptr, nullptr);
  k_loop_ale<<<(N + 255) / 256, 256, 0, stream>>>(rowptr, csr, ale, N, E);
  // layer 1
  k_gemm<true, 0, true><<<dim3((N + 63) / 64, 4), 256, 0, stream>>>(
      x, W1t, hs, N, 256, 192, 0, as1, ad1, als1, ald1);
  k_agg<16, 0><<<(N + 15) / 16, 256, 0, stream>>>(
      hs, rowptr, csr, ale + 0 * EN * 4, als1, ald1, b1, h1, nullptr, N, E);
  // layer 2
  k_gemm<false, 0, true><<<dim3((N + 63) / 64, 4), 256, 0, stream>>>(
      h1, W2t, hs, N, 256, 256, 0, as2, ad2, als2, ald2);
  k_agg<16, 0><<<(N + 15) / 16, 256, 0, stream>>>(
      hs, rowptr, csr, ale + 1 * EN * 4, als2, ald2, b2, h2, nullptr, N, E);
  // layer 3
  k_gemm<false, 0, true><<<dim3((N + 63) / 64, 8), 256, 0, stream>>>(
      h2, W3t, hs, N, 512, 256, 0, as3, ad3, als3, ald3);
  k_agg<32, 1><<<(N + 15) / 16, 256, 0, stream>>>(
      hs, rowptr, csr, ale + 2 * EN * 4, als3, ald3, b3, nullptr, out3, N, E);
  // pool + head
  k_pool<<<64, 256, 0, stream>>>(out3, bat, g, cntb, N);
  k_final<<<64, 320, 0, stream>>>(g, cntb, Wa, ba, Wv, bv, (float*)d_out);
}